// Round 13
// baseline (229.925 us; speedup 1.0000x reference)
//
#include <hip/hip_runtime.h>
#include <hip/hip_fp16.h>

#define NPB   512   // nodes per bucket (2^9)
#define NBMAX 256   // max buckets (N <= 131072)
#define CHUNK 2048  // edges per fillB block (8 per thread)

using f16x4 = __attribute__((ext_vector_type(4))) _Float16;
using f32x4 = __attribute__((ext_vector_type(4))) float;

__device__ __forceinline__ int edge_at(const void* ei, int is64, long long pos) {
  return is64 ? (int)((const long long*)ei)[pos] : ((const int*)ei)[pos];
}

// ---------------- fillB: bucket-partition edges, register-staged ------------
// Per chunk: detect dtype in-block, count per-bucket in LDS, reserve global
// runs (bcur holds COUNTS, zeroed by memset; capacity base added here),
// write directly. int64 node indices < 2^31 have zero high words; for real
// int32 data, 64 consecutive odd words all being zero is impossible.
__global__ __launch_bounds__(256) void k_fillB(const void* __restrict__ ei,
                                               int E, int cap,
                                               int* __restrict__ bcur,
                                               int* __restrict__ tmp, int nb) {
  __shared__ int cntL[NBMAX], gofs[NBMAX], curL[NBMAX];
  __shared__ int sflag;
  int t = threadIdx.x;
  if (t == 0) sflag = 1;
  __syncthreads();
  if (t < 64 && ((const int*)ei)[2 * t + 1] != 0) sflag = 0;
  cntL[t] = 0;
  __syncthreads();
  int is64 = sflag;
  long long base = (long long)blockIdx.x * CHUNK;
  if (base >= E) return;
  int m = (int)min((long long)CHUNK, (long long)E - base);
  int val[8];
  int bkt[8];
#pragma unroll
  for (int i = 0; i < 8; ++i) {
    int idx = t + i * 256;
    if (idx < m) {
      int r = edge_at(ei, is64, base + idx);
      int c = edge_at(ei, is64, (long long)E + base + idx);
      int b = c >> 9;
      val[i] = ((c & 511) << 17) | r;
      bkt[i] = b;
      atomicAdd(&cntL[b], 1);
    }
  }
  __syncthreads();
  if (t < nb) {
    int c = cntL[t];
    gofs[t] = (c ? atomicAdd(&bcur[t], c) : 0) + t * cap;
    curL[t] = 0;
  }
  __syncthreads();
#pragma unroll
  for (int i = 0; i < 8; ++i) {
    if (t + i * 256 < m) {
      int b = bkt[i];
      int p = atomicAdd(&curL[b], 1);
      tmp[gofs[b] + p] = val[i];
    }
  }
}

// ---------------- fillC: per-bucket CSR finalize + rowptr + dis -------------
// 512 threads = 1 node/thread. Each block redundantly scans the bucket counts
// (bcur) in LDS to get its global output base -- no separate bscan kernel.
__global__ __launch_bounds__(512) void k_fillC(const int* __restrict__ tmp,
                                               const int* __restrict__ bcur,
                                               int cap, int* __restrict__ rowptr,
                                               float* __restrict__ dis,
                                               int* __restrict__ esrc,
                                               int N, int nb) {
  __shared__ int cnt[NPB];
  __shared__ int loc[NPB];
  __shared__ int sh[NPB];
  __shared__ int bb[NBMAX];
  int b = blockIdx.x, t = threadIdx.x;
  int count = bcur[b];
  int beg = b * cap;
  int end = beg + count;
  int base_node = b << 9;
  // bucket-count scan (all blocks redundantly): bb -> inclusive prefix
  if (t < NBMAX) bb[t] = (t < nb) ? bcur[t] : 0;
  cnt[t] = 0;
  __syncthreads();
  for (int off = 1; off < NBMAX; off <<= 1) {
    int x = 0;
    if (t >= off && t < NBMAX) x = bb[t - off];
    __syncthreads();
    if (t >= off && t < NBMAX) bb[t] += x;
    __syncthreads();
  }
  int outb = b ? bb[b - 1] : 0;
  if (b == 0 && t == 0) rowptr[N] = bb[nb - 1];
  // per-node histogram
  for (int e = beg + t; e < end; e += 512)
    atomicAdd(&cnt[tmp[e] >> 17], 1);
  __syncthreads();
  int c0 = cnt[t];
  sh[t] = c0;
  __syncthreads();
  for (int off = 1; off < NPB; off <<= 1) {
    int x = 0;
    if (t >= off) x = sh[t - off];
    __syncthreads();
    if (t >= off) sh[t] += x;
    __syncthreads();
  }
  int pre = t ? sh[t - 1] : 0;
  loc[t] = outb + pre;
  int v = base_node + t;
  if (v < N) {
    rowptr[v] = outb + pre;
    dis[v] = rsqrtf((float)(c0 + 2));
  }
  __syncthreads();
  for (int e = beg + t; e < end; e += 512) {
    int u = tmp[e];
    int pos = atomicAdd(&loc[u >> 17], 1);
    esrc[pos] = u & 0x1FFFF;
  }
}

// ---------------- MFMA GEMM, W-in-registers: C = dis .* (A @ W) (fp16) -----
// BN*4 threads = BN/16 waves; wave w owns output cols [w*16, w*16+16).
// Its B-fragments (8 k-steps x f16x4 = 16 VGPRs) live in registers; LDS holds
// only the A tile (17.7 KB) -> high occupancy. mfma_f32_16x16x16f16 frags:
// A row=lane&15, k=(lane>>4)*4+i; B col=lane&15 same k;
// D col=lane&15, row=(lane>>4)*4+reg.
template <int BN, bool AHALF, bool PRESCALE>
__global__ __launch_bounds__(BN * 4) void k_gemm(const void* __restrict__ Av,
                                                 const float* __restrict__ W,
                                                 const float* __restrict__ dis,
                                                 __half* __restrict__ C,
                                                 int M, int tiles) {
  constexpr int THREADS = BN * 4;
  constexpr int CH = BN / 4;
  __shared__ _Float16 At[64][136];   // A tile [row][k]; reused for C staging
  __shared__ float disL[64];
  int t = threadIdx.x;
  int lane = t & 63, w = t >> 6;
  int lrow = lane & 15;
  int kq = (lane >> 4) * 4;          // k offset within 16-step
  int col = w * 16 + lrow;           // this lane's output column

  // B fragments in registers: W row-major [128][BN] fp32, column-strided reads
  f16x4 bfrag[8];
#pragma unroll
  for (int k8 = 0; k8 < 8; ++k8) {
    int kb = k8 * 16 + kq;
    bfrag[k8] = f16x4{(_Float16)W[(size_t)(kb + 0) * BN + col],
                      (_Float16)W[(size_t)(kb + 1) * BN + col],
                      (_Float16)W[(size_t)(kb + 2) * BN + col],
                      (_Float16)W[(size_t)(kb + 3) * BN + col]};
  }

  for (int tile = blockIdx.x; tile < tiles; tile += gridDim.x) {
    int row0 = tile * 64;
    __syncthreads();  // At free for staging
    // stage A tile: 64 rows x 128 k (fp16), 4B-chunk layout
#pragma unroll
    for (int i = 0; i < (64 * 32) / THREADS; ++i) {
      int idx = t + i * THREADS;
      int r = idx >> 5, c = (idx & 31) * 4;
      int gr = row0 + r;
      f16x4 hv = {0, 0, 0, 0};
      if (gr < M) {
        if constexpr (AHALF) {
          hv = *(const f16x4*)&((const _Float16*)Av)[(size_t)gr * 128 + c];
        } else {
          float4 v = *(const float4*)&((const float*)Av)[(size_t)gr * 128 + c];
          hv = f16x4{(_Float16)v.x, (_Float16)v.y, (_Float16)v.z, (_Float16)v.w};
        }
      }
      *(f16x4*)&At[r][c] = hv;
    }
    if constexpr (PRESCALE) {
      if (t < 64) {
        int gr = row0 + t;
        disL[t] = (gr < M) ? dis[gr] : 0.f;
      }
    }
    __syncthreads();
    // compute: wave w -> rows 0..63 of cols [w*16, w*16+16)
    f32x4 acc[4];
#pragma unroll
    for (int mt = 0; mt < 4; ++mt) acc[mt] = f32x4{0.f, 0.f, 0.f, 0.f};
#pragma unroll
    for (int k8 = 0; k8 < 8; ++k8) {
      int kk = k8 * 16 + kq;
      f16x4 a[4];
#pragma unroll
      for (int mt = 0; mt < 4; ++mt)
        a[mt] = *(const f16x4*)&At[mt * 16 + lrow][kk];
#pragma unroll
      for (int mt = 0; mt < 4; ++mt)
        acc[mt] = __builtin_amdgcn_mfma_f32_16x16x16f16(a[mt], bfrag[k8],
                                                        acc[mt], 0, 0, 0);
    }
    __syncthreads();  // all waves done reading At
    // stage C tile into At (as [row][col]), optionally prescaled by dis[row]
#pragma unroll
    for (int mt = 0; mt < 4; ++mt) {
      int rr = mt * 16 + kq;
#pragma unroll
      for (int reg = 0; reg < 4; ++reg) {
        float val = acc[mt][reg];
        if constexpr (PRESCALE) val *= disL[rr + reg];
        At[rr + reg][col] = (_Float16)val;
      }
    }
    __syncthreads();
    // coalesced global store, 8 B per thread-chunk
#pragma unroll
    for (int i = 0; i < (64 * CH) / THREADS; ++i) {
      int idx = t + i * THREADS;
      int r = idx / CH, c = (idx % CH) * 4;
      int gr = row0 + r;
      if (gr < M)
        *(f16x4*)&C[(size_t)gr * BN + c] = *(const f16x4*)&At[r][c];
    }
  }
}

// accumulate 4 fp16 features (one uint2) into 4 fp32 accumulators
#define ACC4(u)                                                         \
  { __half2 p;                                                          \
    p = *(__half2*)&(u).x; a0 += __low2float(p); a1 += __high2float(p); \
    p = *(__half2*)&(u).y; a2 += __low2float(p); a3 += __high2float(p); }

// ---------------- FUSED gather128 + gemm2: t2 = dis .* (z @ W2) ------------
// Wave g owns nodes [16g, 16g+16). Per node: gather (prescaled t1 rows) ->
// z = relu(dv*(2*t[v]+sum)+b1) in registers -> fp16 ds_write into the wave's
// private LDS tile Z[16][128]. Then 4 col-tiles x 8 k-steps of MFMA with
// B-fragments loaded fresh from L2-hot W2; D prescaled by dis and stored to
// t2 directly. z never touches global memory. No __syncthreads (wave-private
// LDS). mfma frags: A row=lane&15, k=(lane>>4)*4+i; D col=lane&15,
// row=(lane>>4)*4+reg.
__global__ __launch_bounds__(256) void k_gfuse(const __half* __restrict__ t,
    const float* __restrict__ bias, const int* __restrict__ rowptr,
    const int* __restrict__ esrc, const float* __restrict__ dis,
    const float* __restrict__ W2, __half* __restrict__ t2, int n) {
  __shared__ _Float16 Z[4][16][132];  // pad 132: row stride 264 B
  __shared__ float disS[4][16];
  int w = threadIdx.x >> 6;
  int lane = threadIdx.x & 63;
  int g = blockIdx.x * 4 + w;
  int v0 = g * 16;
  if (v0 >= n) return;
  int half = lane >> 5;
  int f = (lane & 31) * 4;
  int lrow = lane & 15;
  int kq = (lane >> 4) * 4;
  if (lane < 16) disS[w][lane] = (v0 + lane < n) ? dis[v0 + lane] : 0.f;
  float bb0 = bias[f], bb1 = bias[f + 1], bb2 = bias[f + 2], bb3 = bias[f + 3];

  for (int nb_ = 0; nb_ < 16; ++nb_) {
    int v = v0 + nb_;
    float a0 = 0.f, a1 = 0.f, a2 = 0.f, a3 = 0.f;
    if (v < n) {
      int beg = rowptr[v], end = rowptr[v + 1];
      int e = beg + half;
      for (; e + 14 < end; e += 16) {  // 8 edges per half-wave in flight
        int s0 = esrc[e],      s1 = esrc[e + 2],  s2 = esrc[e + 4],  s3 = esrc[e + 6];
        int s4 = esrc[e + 8],  s5 = esrc[e + 10], s6 = esrc[e + 12], s7 = esrc[e + 14];
        uint2 u0 = *(const uint2*)&t[(size_t)s0 * 128 + f];
        uint2 u1 = *(const uint2*)&t[(size_t)s1 * 128 + f];
        uint2 u2 = *(const uint2*)&t[(size_t)s2 * 128 + f];
        uint2 u3 = *(const uint2*)&t[(size_t)s3 * 128 + f];
        uint2 u4 = *(const uint2*)&t[(size_t)s4 * 128 + f];
        uint2 u5 = *(const uint2*)&t[(size_t)s5 * 128 + f];
        uint2 u6 = *(const uint2*)&t[(size_t)s6 * 128 + f];
        uint2 u7 = *(const uint2*)&t[(size_t)s7 * 128 + f];
        ACC4(u0) ACC4(u1) ACC4(u2) ACC4(u3)
        ACC4(u4) ACC4(u5) ACC4(u6) ACC4(u7)
      }
      for (; e + 6 < end; e += 8) {    // 4 edges
        int s0 = esrc[e], s1 = esrc[e + 2], s2 = esrc[e + 4], s3 = esrc[e + 6];
        uint2 u0 = *(const uint2*)&t[(size_t)s0 * 128 + f];
        uint2 u1 = *(const uint2*)&t[(size_t)s1 * 128 + f];
        uint2 u2 = *(const uint2*)&t[(size_t)s2 * 128 + f];
        uint2 u3 = *(const uint2*)&t[(size_t)s3 * 128 + f];
        ACC4(u0) ACC4(u1) ACC4(u2) ACC4(u3)
      }
      for (; e < end; e += 2) {
        int s0 = esrc[e];
        uint2 u0 = *(const uint2*)&t[(size_t)s0 * 128 + f];
        ACC4(u0)
      }
      if (half == 0) {  // self term: 2 * prescaled row
        uint2 uv = *(const uint2*)&t[(size_t)v * 128 + f];
        __half2 p;
        p = *(__half2*)&uv.x; a0 = fmaf(2.f, __low2float(p), a0); a1 = fmaf(2.f, __high2float(p), a1);
        p = *(__half2*)&uv.y; a2 = fmaf(2.f, __low2float(p), a2); a3 = fmaf(2.f, __high2float(p), a3);
      }
    }
    a0 += __shfl_xor(a0, 32); a1 += __shfl_xor(a1, 32);
    a2 += __shfl_xor(a2, 32); a3 += __shfl_xor(a3, 32);
    if (half == 0) {
      float dv = disS[w][nb_];
      a0 = fmaxf(fmaf(dv, a0, bb0), 0.f);
      a1 = fmaxf(fmaf(dv, a1, bb1), 0.f);
      a2 = fmaxf(fmaf(dv, a2, bb2), 0.f);
      a3 = fmaxf(fmaf(dv, a3, bb3), 0.f);
      *(f16x4*)&Z[w][nb_][f] = f16x4{(_Float16)a0, (_Float16)a1,
                                     (_Float16)a2, (_Float16)a3};
    }
  }
  // MFMA phase: t2[v0+rr][0..63] = disS[rr] * (Z row rr @ W2)
#pragma unroll
  for (int nt = 0; nt < 4; ++nt) {
    f32x4 acc = {0.f, 0.f, 0.f, 0.f};
    int col = nt * 16 + lrow;
#pragma unroll
    for (int k8 = 0; k8 < 8; ++k8) {
      int kb = k8 * 16 + kq;
      f16x4 a = *(const f16x4*)&Z[w][lrow][kb];
      f16x4 b = f16x4{(_Float16)W2[(size_t)(kb + 0) * 64 + col],
                      (_Float16)W2[(size_t)(kb + 1) * 64 + col],
                      (_Float16)W2[(size_t)(kb + 2) * 64 + col],
                      (_Float16)W2[(size_t)(kb + 3) * 64 + col]};
      acc = __builtin_amdgcn_mfma_f32_16x16x16f16(a, b, acc, 0, 0, 0);
    }
#pragma unroll
    for (int reg = 0; reg < 4; ++reg) {
      int rr = kq + reg;
      int gv = v0 + rr;
      if (gv < n)
        t2[(size_t)gv * 64 + col] = (_Float16)(acc[reg] * disS[w][rr]);
    }
  }
}

// ---------------- gather 64, 4 quarter-wave groups per node ----------------
// Input rows PRESCALED by dis[src]; fp32 out = dis[v]*(2*t[v]+sum) + b.
__global__ __launch_bounds__(256) void k_gather64(const __half* __restrict__ t,
    const float* __restrict__ bias, const int* __restrict__ rowptr,
    const int* __restrict__ esrc, const float* __restrict__ dis,
    float* __restrict__ o, int n) {
  int gw = (int)((blockIdx.x * blockDim.x + threadIdx.x) >> 6);
  int lane = threadIdx.x & 63;
  int nw = (int)((gridDim.x * blockDim.x) >> 6);
  int sub = lane >> 4;
  int f = (lane & 15) * 4;
  for (int v = gw; v < n; v += nw) {
    float a0 = 0.f, a1 = 0.f, a2 = 0.f, a3 = 0.f;
    int beg = rowptr[v], end = rowptr[v + 1];
    int e = beg + sub;
    for (; e + 28 < end; e += 32) {  // 8 edges per quarter-wave in flight
      int s0 = esrc[e],      s1 = esrc[e + 4],  s2 = esrc[e + 8],  s3 = esrc[e + 12];
      int s4 = esrc[e + 16], s5 = esrc[e + 20], s6 = esrc[e + 24], s7 = esrc[e + 28];
      uint2 u0 = *(const uint2*)&t[(size_t)s0 * 64 + f];
      uint2 u1 = *(const uint2*)&t[(size_t)s1 * 64 + f];
      uint2 u2 = *(const uint2*)&t[(size_t)s2 * 64 + f];
      uint2 u3 = *(const uint2*)&t[(size_t)s3 * 64 + f];
      uint2 u4 = *(const uint2*)&t[(size_t)s4 * 64 + f];
      uint2 u5 = *(const uint2*)&t[(size_t)s5 * 64 + f];
      uint2 u6 = *(const uint2*)&t[(size_t)s6 * 64 + f];
      uint2 u7 = *(const uint2*)&t[(size_t)s7 * 64 + f];
      ACC4(u0) ACC4(u1) ACC4(u2) ACC4(u3)
      ACC4(u4) ACC4(u5) ACC4(u6) ACC4(u7)
    }
    for (; e + 12 < end; e += 16) {  // 4 edges
      int s0 = esrc[e], s1 = esrc[e + 4], s2 = esrc[e + 8], s3 = esrc[e + 12];
      uint2 u0 = *(const uint2*)&t[(size_t)s0 * 64 + f];
      uint2 u1 = *(const uint2*)&t[(size_t)s1 * 64 + f];
      uint2 u2 = *(const uint2*)&t[(size_t)s2 * 64 + f];
      uint2 u3 = *(const uint2*)&t[(size_t)s3 * 64 + f];
      ACC4(u0) ACC4(u1) ACC4(u2) ACC4(u3)
    }
    for (; e < end; e += 4) {
      int s0 = esrc[e];
      uint2 u0 = *(const uint2*)&t[(size_t)s0 * 64 + f];
      ACC4(u0)
    }
    if (sub == 0) {  // self term
      uint2 uv = *(const uint2*)&t[(size_t)v * 64 + f];
      __half2 p;
      p = *(__half2*)&uv.x; a0 = fmaf(2.f, __low2float(p), a0); a1 = fmaf(2.f, __high2float(p), a1);
      p = *(__half2*)&uv.y; a2 = fmaf(2.f, __low2float(p), a2); a3 = fmaf(2.f, __high2float(p), a3);
    }
    a0 += __shfl_xor(a0, 16); a0 += __shfl_xor(a0, 32);
    a1 += __shfl_xor(a1, 16); a1 += __shfl_xor(a1, 32);
    a2 += __shfl_xor(a2, 16); a2 += __shfl_xor(a2, 32);
    a3 += __shfl_xor(a3, 16); a3 += __shfl_xor(a3, 32);
    if (sub == 0) {
      float dv = dis[v];
      float4 r;
      r.x = fmaf(dv, a0, bias[f]);     r.y = fmaf(dv, a1, bias[f + 1]);
      r.z = fmaf(dv, a2, bias[f + 2]); r.w = fmaf(dv, a3, bias[f + 3]);
      *(float4*)&o[(size_t)v * 64 + f] = r;
    }
  }
}

extern "C" void kernel_launch(void* const* d_in, const int* in_sizes, int n_in,
                              void* d_out, int out_size, void* d_ws, size_t ws_size,
                              hipStream_t stream) {
  const float* x  = (const float*)d_in[0];
  const void*  ei = d_in[1];
  const float* W1 = (const float*)d_in[2];
  const float* b1 = (const float*)d_in[3];
  const float* W2 = (const float*)d_in[4];
  const float* b2 = (const float*)d_in[5];
  const int N = in_sizes[0] / 128;
  const int E = in_sizes[1] / 2;
  float* out = (float*)d_out;
  const int nb  = (N + NPB - 1) / NPB;       // 196 buckets for N=100000
  const int cap = E / nb + 4096;             // generous per-bucket capacity

  size_t off = 0;
  auto alloc = [&](size_t bytes) -> void* {
    void* p = (char*)d_ws + off;
    off += (bytes + 255) & ~(size_t)255;
    return p;
  };
  int*    bcur   = (int*)alloc(NBMAX * 4);
  int*    rowptr = (int*)alloc(((size_t)N + 1) * 4);
  float*  dis    = (float*)alloc((size_t)N * 4);
  int*    tmp    = (int*)alloc(((size_t)nb * cap + 16384) * 4);
  int*    esrc   = (int*)alloc((size_t)E * 4);
  __half* t1     = (__half*)alloc((size_t)N * 128 * 2);
  __half* t2     = (__half*)alloc((size_t)N * 64 * 2);  // NOT aliased: k_gfuse reads t1 while writing t2

  int tiles = (N + 63) / 64;
  int nchunks = (E + CHUNK - 1) / CHUNK;

  // CSR build first so dis is ready for gemm1's prescale epilogue
  hipMemsetAsync(bcur, 0, NBMAX * 4, stream);
  k_fillB<<<nchunks, 256, 0, stream>>>(ei, E, cap, bcur, tmp, nb);
  k_fillC<<<nb, 512, 0, stream>>>(tmp, bcur, cap, rowptr, dis, esrc, N, nb);

  // layer 1: t1 = dis .* (x @ W1) (fp16)
  k_gemm<128, false, true><<<tiles, 512, 0, stream>>>(x, W1, dis, t1, N, tiles);
  // fused: z = relu(dv*(2*t1[v]+sum)+b1) in-wave; t2 = dis .* (z @ W2)
  k_gfuse<<<(N + 63) / 64, 256, 0, stream>>>(t1, b1, rowptr, esrc, dis, W2, t2, N);
  // layer 2 propagate: out = dv*(2*t2[v]+sum) + b2 (fp32)
  k_gather64<<<2048, 256, 0, stream>>>(t2, b2, rowptr, esrc, dis, out, N);
}

// Round 14
// 199.118 us; speedup vs baseline: 1.1547x; 1.1547x over previous
//
#include <hip/hip_runtime.h>
#include <hip/hip_fp16.h>

#define NPB   512   // nodes per bucket (2^9)
#define NBMAX 256   // max buckets (N <= 131072)
#define CHUNK 2048  // edges per fillB block (8 per thread)

using f16x4 = __attribute__((ext_vector_type(4))) _Float16;
using f32x4 = __attribute__((ext_vector_type(4))) float;

__device__ __forceinline__ int edge_at(const void* ei, int is64, long long pos) {
  return is64 ? (int)((const long long*)ei)[pos] : ((const int*)ei)[pos];
}

// ---------------- fillB: bucket-partition edges, register-staged ------------
// Per chunk: detect dtype in-block, count per-bucket in LDS, reserve global
// runs (bcur holds COUNTS, zeroed by memset; capacity base added here),
// write directly. int64 node indices < 2^31 have zero high words; for real
// int32 data, 64 consecutive odd words all being zero is impossible.
__global__ __launch_bounds__(256) void k_fillB(const void* __restrict__ ei,
                                               int E, int cap,
                                               int* __restrict__ bcur,
                                               int* __restrict__ tmp, int nb) {
  __shared__ int cntL[NBMAX], gofs[NBMAX], curL[NBMAX];
  __shared__ int sflag;
  int t = threadIdx.x;
  if (t == 0) sflag = 1;
  __syncthreads();
  if (t < 64 && ((const int*)ei)[2 * t + 1] != 0) sflag = 0;
  cntL[t] = 0;
  __syncthreads();
  int is64 = sflag;
  long long base = (long long)blockIdx.x * CHUNK;
  if (base >= E) return;
  int m = (int)min((long long)CHUNK, (long long)E - base);
  int val[8];
  int bkt[8];
#pragma unroll
  for (int i = 0; i < 8; ++i) {
    int idx = t + i * 256;
    if (idx < m) {
      int r = edge_at(ei, is64, base + idx);
      int c = edge_at(ei, is64, (long long)E + base + idx);
      int b = c >> 9;
      val[i] = ((c & 511) << 17) | r;
      bkt[i] = b;
      atomicAdd(&cntL[b], 1);
    }
  }
  __syncthreads();
  if (t < nb) {
    int c = cntL[t];
    gofs[t] = (c ? atomicAdd(&bcur[t], c) : 0) + t * cap;
    curL[t] = 0;
  }
  __syncthreads();
#pragma unroll
  for (int i = 0; i < 8; ++i) {
    if (t + i * 256 < m) {
      int b = bkt[i];
      int p = atomicAdd(&curL[b], 1);
      tmp[gofs[b] + p] = val[i];
    }
  }
}

// ---------------- fillC: per-bucket CSR finalize + rowptr + dis -------------
// 512 threads = 1 node/thread. Each block redundantly scans the bucket counts
// (bcur) in LDS to get its global output base -- no separate bscan kernel.
__global__ __launch_bounds__(512) void k_fillC(const int* __restrict__ tmp,
                                               const int* __restrict__ bcur,
                                               int cap, int* __restrict__ rowptr,
                                               float* __restrict__ dis,
                                               int* __restrict__ esrc,
                                               int N, int nb) {
  __shared__ int cnt[NPB];
  __shared__ int loc[NPB];
  __shared__ int sh[NPB];
  __shared__ int bb[NBMAX];
  int b = blockIdx.x, t = threadIdx.x;
  int count = bcur[b];
  int beg = b * cap;
  int end = beg + count;
  int base_node = b << 9;
  // bucket-count scan (all blocks redundantly): bb -> inclusive prefix
  if (t < NBMAX) bb[t] = (t < nb) ? bcur[t] : 0;
  cnt[t] = 0;
  __syncthreads();
  for (int off = 1; off < NBMAX; off <<= 1) {
    int x = 0;
    if (t >= off && t < NBMAX) x = bb[t - off];
    __syncthreads();
    if (t >= off && t < NBMAX) bb[t] += x;
    __syncthreads();
  }
  int outb = b ? bb[b - 1] : 0;
  if (b == 0 && t == 0) rowptr[N] = bb[nb - 1];
  // per-node histogram
  for (int e = beg + t; e < end; e += 512)
    atomicAdd(&cnt[tmp[e] >> 17], 1);
  __syncthreads();
  int c0 = cnt[t];
  sh[t] = c0;
  __syncthreads();
  for (int off = 1; off < NPB; off <<= 1) {
    int x = 0;
    if (t >= off) x = sh[t - off];
    __syncthreads();
    if (t >= off) sh[t] += x;
    __syncthreads();
  }
  int pre = t ? sh[t - 1] : 0;
  loc[t] = outb + pre;
  int v = base_node + t;
  if (v < N) {
    rowptr[v] = outb + pre;
    dis[v] = rsqrtf((float)(c0 + 2));
  }
  __syncthreads();
  for (int e = beg + t; e < end; e += 512) {
    int u = tmp[e];
    int pos = atomicAdd(&loc[u >> 17], 1);
    esrc[pos] = u & 0x1FFFF;
  }
}

// ---------------- MFMA GEMM, W-in-registers: C = dis .* (A @ W) (fp16) -----
// BN*4 threads = BN/16 waves; wave w owns output cols [w*16, w*16+16).
// Its B-fragments (8 k-steps x f16x4 = 16 VGPRs) live in registers; LDS holds
// only the A tile (17.7 KB) -> high occupancy. mfma_f32_16x16x16f16 frags:
// A row=lane&15, k=(lane>>4)*4+i; B col=lane&15 same k;
// D col=lane&15, row=(lane>>4)*4+reg.
template <int BN, bool AHALF, bool PRESCALE>
__global__ __launch_bounds__(BN * 4) void k_gemm(const void* __restrict__ Av,
                                                 const float* __restrict__ W,
                                                 const float* __restrict__ dis,
                                                 __half* __restrict__ C,
                                                 int M, int tiles) {
  constexpr int THREADS = BN * 4;
  constexpr int CH = BN / 4;
  __shared__ _Float16 At[64][136];   // A tile [row][k]; reused for C staging
  __shared__ float disL[64];
  int t = threadIdx.x;
  int lane = t & 63, w = t >> 6;
  int lrow = lane & 15;
  int kq = (lane >> 4) * 4;          // k offset within 16-step
  int col = w * 16 + lrow;           // this lane's output column

  // B fragments in registers: W row-major [128][BN] fp32, column-strided reads
  f16x4 bfrag[8];
#pragma unroll
  for (int k8 = 0; k8 < 8; ++k8) {
    int kb = k8 * 16 + kq;
    bfrag[k8] = f16x4{(_Float16)W[(size_t)(kb + 0) * BN + col],
                      (_Float16)W[(size_t)(kb + 1) * BN + col],
                      (_Float16)W[(size_t)(kb + 2) * BN + col],
                      (_Float16)W[(size_t)(kb + 3) * BN + col]};
  }

  for (int tile = blockIdx.x; tile < tiles; tile += gridDim.x) {
    int row0 = tile * 64;
    __syncthreads();  // At free for staging
    // stage A tile: 64 rows x 128 k (fp16), 4B-chunk layout
#pragma unroll
    for (int i = 0; i < (64 * 32) / THREADS; ++i) {
      int idx = t + i * THREADS;
      int r = idx >> 5, c = (idx & 31) * 4;
      int gr = row0 + r;
      f16x4 hv = {0, 0, 0, 0};
      if (gr < M) {
        if constexpr (AHALF) {
          hv = *(const f16x4*)&((const _Float16*)Av)[(size_t)gr * 128 + c];
        } else {
          float4 v = *(const float4*)&((const float*)Av)[(size_t)gr * 128 + c];
          hv = f16x4{(_Float16)v.x, (_Float16)v.y, (_Float16)v.z, (_Float16)v.w};
        }
      }
      *(f16x4*)&At[r][c] = hv;
    }
    if constexpr (PRESCALE) {
      if (t < 64) {
        int gr = row0 + t;
        disL[t] = (gr < M) ? dis[gr] : 0.f;
      }
    }
    __syncthreads();
    // compute: wave w -> rows 0..63 of cols [w*16, w*16+16)
    f32x4 acc[4];
#pragma unroll
    for (int mt = 0; mt < 4; ++mt) acc[mt] = f32x4{0.f, 0.f, 0.f, 0.f};
#pragma unroll
    for (int k8 = 0; k8 < 8; ++k8) {
      int kk = k8 * 16 + kq;
      f16x4 a[4];
#pragma unroll
      for (int mt = 0; mt < 4; ++mt)
        a[mt] = *(const f16x4*)&At[mt * 16 + lrow][kk];
#pragma unroll
      for (int mt = 0; mt < 4; ++mt)
        acc[mt] = __builtin_amdgcn_mfma_f32_16x16x16f16(a[mt], bfrag[k8],
                                                        acc[mt], 0, 0, 0);
    }
    __syncthreads();  // all waves done reading At
    // stage C tile into At (as [row][col]), optionally prescaled by dis[row]
#pragma unroll
    for (int mt = 0; mt < 4; ++mt) {
      int rr = mt * 16 + kq;
#pragma unroll
      for (int reg = 0; reg < 4; ++reg) {
        float val = acc[mt][reg];
        if constexpr (PRESCALE) val *= disL[rr + reg];
        At[rr + reg][col] = (_Float16)val;
      }
    }
    __syncthreads();
    // coalesced global store, 8 B per thread-chunk
#pragma unroll
    for (int i = 0; i < (64 * CH) / THREADS; ++i) {
      int idx = t + i * THREADS;
      int r = idx / CH, c = (idx % CH) * 4;
      int gr = row0 + r;
      if (gr < M)
        *(f16x4*)&C[(size_t)gr * BN + c] = *(const f16x4*)&At[r][c];
    }
  }
}

// accumulate 4 fp16 features (one uint2) into 4 fp32 accumulators
#define ACC4(u)                                                         \
  { __half2 p;                                                          \
    p = *(__half2*)&(u).x; a0 += __low2float(p); a1 += __high2float(p); \
    p = *(__half2*)&(u).y; a2 += __low2float(p); a3 += __high2float(p); }

// ---------------- gather 128, 2 half-waves per node -------------------------
// Input rows PRESCALED by dis[src]: out = relu(dv*(2*t[v]+sum) + b).
// Each half-wave covers a full 256 B row: 32 lanes x uint2 (4 features).
__global__ __launch_bounds__(256) void k_gather128(const __half* __restrict__ t,
    const float* __restrict__ bias, const int* __restrict__ rowptr,
    const int* __restrict__ esrc, const float* __restrict__ dis,
    __half* __restrict__ o, int n) {
  int gw = (int)((blockIdx.x * blockDim.x + threadIdx.x) >> 6);
  int lane = threadIdx.x & 63;
  int nw = (int)((gridDim.x * blockDim.x) >> 6);
  int half = lane >> 5;
  int f = (lane & 31) * 4;
  for (int v = gw; v < n; v += nw) {
    float a0 = 0.f, a1 = 0.f, a2 = 0.f, a3 = 0.f;
    int beg = rowptr[v], end = rowptr[v + 1];
    int e = beg + half;
    for (; e + 14 < end; e += 16) {  // 8 edges per half-wave in flight
      int s0 = esrc[e],      s1 = esrc[e + 2],  s2 = esrc[e + 4],  s3 = esrc[e + 6];
      int s4 = esrc[e + 8],  s5 = esrc[e + 10], s6 = esrc[e + 12], s7 = esrc[e + 14];
      uint2 u0 = *(const uint2*)&t[(size_t)s0 * 128 + f];
      uint2 u1 = *(const uint2*)&t[(size_t)s1 * 128 + f];
      uint2 u2 = *(const uint2*)&t[(size_t)s2 * 128 + f];
      uint2 u3 = *(const uint2*)&t[(size_t)s3 * 128 + f];
      uint2 u4 = *(const uint2*)&t[(size_t)s4 * 128 + f];
      uint2 u5 = *(const uint2*)&t[(size_t)s5 * 128 + f];
      uint2 u6 = *(const uint2*)&t[(size_t)s6 * 128 + f];
      uint2 u7 = *(const uint2*)&t[(size_t)s7 * 128 + f];
      ACC4(u0) ACC4(u1) ACC4(u2) ACC4(u3)
      ACC4(u4) ACC4(u5) ACC4(u6) ACC4(u7)
    }
    for (; e + 6 < end; e += 8) {    // 4 edges
      int s0 = esrc[e], s1 = esrc[e + 2], s2 = esrc[e + 4], s3 = esrc[e + 6];
      uint2 u0 = *(const uint2*)&t[(size_t)s0 * 128 + f];
      uint2 u1 = *(const uint2*)&t[(size_t)s1 * 128 + f];
      uint2 u2 = *(const uint2*)&t[(size_t)s2 * 128 + f];
      uint2 u3 = *(const uint2*)&t[(size_t)s3 * 128 + f];
      ACC4(u0) ACC4(u1) ACC4(u2) ACC4(u3)
    }
    for (; e < end; e += 2) {
      int s0 = esrc[e];
      uint2 u0 = *(const uint2*)&t[(size_t)s0 * 128 + f];
      ACC4(u0)
    }
    if (half == 0) {  // self term: 2 * prescaled row
      uint2 uv = *(const uint2*)&t[(size_t)v * 128 + f];
      __half2 p;
      p = *(__half2*)&uv.x; a0 = fmaf(2.f, __low2float(p), a0); a1 = fmaf(2.f, __high2float(p), a1);
      p = *(__half2*)&uv.y; a2 = fmaf(2.f, __low2float(p), a2); a3 = fmaf(2.f, __high2float(p), a3);
    }
    a0 += __shfl_xor(a0, 32); a1 += __shfl_xor(a1, 32);
    a2 += __shfl_xor(a2, 32); a3 += __shfl_xor(a3, 32);
    if (half == 0) {
      float dv = dis[v];
      a0 = fmaxf(fmaf(dv, a0, bias[f]),     0.f);
      a1 = fmaxf(fmaf(dv, a1, bias[f + 1]), 0.f);
      a2 = fmaxf(fmaf(dv, a2, bias[f + 2]), 0.f);
      a3 = fmaxf(fmaf(dv, a3, bias[f + 3]), 0.f);
      __half2 h0 = __floats2half2_rn(a0, a1), h1 = __floats2half2_rn(a2, a3);
      uint2 uu;
      uu.x = *(unsigned int*)&h0; uu.y = *(unsigned int*)&h1;
      *(uint2*)&o[(size_t)v * 128 + f] = uu;
    }
  }
}

// ---------------- gather 64, 4 quarter-wave groups per node ----------------
// Input rows PRESCALED by dis[src]; fp32 out = dis[v]*(2*t[v]+sum) + b.
__global__ __launch_bounds__(256) void k_gather64(const __half* __restrict__ t,
    const float* __restrict__ bias, const int* __restrict__ rowptr,
    const int* __restrict__ esrc, const float* __restrict__ dis,
    float* __restrict__ o, int n) {
  int gw = (int)((blockIdx.x * blockDim.x + threadIdx.x) >> 6);
  int lane = threadIdx.x & 63;
  int nw = (int)((gridDim.x * blockDim.x) >> 6);
  int sub = lane >> 4;
  int f = (lane & 15) * 4;
  for (int v = gw; v < n; v += nw) {
    float a0 = 0.f, a1 = 0.f, a2 = 0.f, a3 = 0.f;
    int beg = rowptr[v], end = rowptr[v + 1];
    int e = beg + sub;
    for (; e + 28 < end; e += 32) {  // 8 edges per quarter-wave in flight
      int s0 = esrc[e],      s1 = esrc[e + 4],  s2 = esrc[e + 8],  s3 = esrc[e + 12];
      int s4 = esrc[e + 16], s5 = esrc[e + 20], s6 = esrc[e + 24], s7 = esrc[e + 28];
      uint2 u0 = *(const uint2*)&t[(size_t)s0 * 64 + f];
      uint2 u1 = *(const uint2*)&t[(size_t)s1 * 64 + f];
      uint2 u2 = *(const uint2*)&t[(size_t)s2 * 64 + f];
      uint2 u3 = *(const uint2*)&t[(size_t)s3 * 64 + f];
      uint2 u4 = *(const uint2*)&t[(size_t)s4 * 64 + f];
      uint2 u5 = *(const uint2*)&t[(size_t)s5 * 64 + f];
      uint2 u6 = *(const uint2*)&t[(size_t)s6 * 64 + f];
      uint2 u7 = *(const uint2*)&t[(size_t)s7 * 64 + f];
      ACC4(u0) ACC4(u1) ACC4(u2) ACC4(u3)
      ACC4(u4) ACC4(u5) ACC4(u6) ACC4(u7)
    }
    for (; e + 12 < end; e += 16) {  // 4 edges
      int s0 = esrc[e], s1 = esrc[e + 4], s2 = esrc[e + 8], s3 = esrc[e + 12];
      uint2 u0 = *(const uint2*)&t[(size_t)s0 * 64 + f];
      uint2 u1 = *(const uint2*)&t[(size_t)s1 * 64 + f];
      uint2 u2 = *(const uint2*)&t[(size_t)s2 * 64 + f];
      uint2 u3 = *(const uint2*)&t[(size_t)s3 * 64 + f];
      ACC4(u0) ACC4(u1) ACC4(u2) ACC4(u3)
    }
    for (; e < end; e += 4) {
      int s0 = esrc[e];
      uint2 u0 = *(const uint2*)&t[(size_t)s0 * 64 + f];
      ACC4(u0)
    }
    if (sub == 0) {  // self term
      uint2 uv = *(const uint2*)&t[(size_t)v * 64 + f];
      __half2 p;
      p = *(__half2*)&uv.x; a0 = fmaf(2.f, __low2float(p), a0); a1 = fmaf(2.f, __high2float(p), a1);
      p = *(__half2*)&uv.y; a2 = fmaf(2.f, __low2float(p), a2); a3 = fmaf(2.f, __high2float(p), a3);
    }
    a0 += __shfl_xor(a0, 16); a0 += __shfl_xor(a0, 32);
    a1 += __shfl_xor(a1, 16); a1 += __shfl_xor(a1, 32);
    a2 += __shfl_xor(a2, 16); a2 += __shfl_xor(a2, 32);
    a3 += __shfl_xor(a3, 16); a3 += __shfl_xor(a3, 32);
    if (sub == 0) {
      float dv = dis[v];
      float4 r;
      r.x = fmaf(dv, a0, bias[f]);     r.y = fmaf(dv, a1, bias[f + 1]);
      r.z = fmaf(dv, a2, bias[f + 2]); r.w = fmaf(dv, a3, bias[f + 3]);
      *(float4*)&o[(size_t)v * 64 + f] = r;
    }
  }
}

extern "C" void kernel_launch(void* const* d_in, const int* in_sizes, int n_in,
                              void* d_out, int out_size, void* d_ws, size_t ws_size,
                              hipStream_t stream) {
  const float* x  = (const float*)d_in[0];
  const void*  ei = d_in[1];
  const float* W1 = (const float*)d_in[2];
  const float* b1 = (const float*)d_in[3];
  const float* W2 = (const float*)d_in[4];
  const float* b2 = (const float*)d_in[5];
  const int N = in_sizes[0] / 128;
  const int E = in_sizes[1] / 2;
  float* out = (float*)d_out;
  const int nb  = (N + NPB - 1) / NPB;       // 196 buckets for N=100000
  const int cap = E / nb + 4096;             // generous per-bucket capacity

  size_t off = 0;
  auto alloc = [&](size_t bytes) -> void* {
    void* p = (char*)d_ws + off;
    off += (bytes + 255) & ~(size_t)255;
    return p;
  };
  int*    bcur   = (int*)alloc(NBMAX * 4);
  int*    rowptr = (int*)alloc(((size_t)N + 1) * 4);
  float*  dis    = (float*)alloc((size_t)N * 4);
  int*    tmp    = (int*)alloc(((size_t)nb * cap + 16384) * 4);
  int*    esrc   = (int*)alloc((size_t)E * 4);
  __half* t1     = (__half*)alloc((size_t)N * 128 * 2);
  __half* z1     = (__half*)alloc((size_t)N * 128 * 2);
  __half* t2     = t1;  // t1 dead once gather1 produced z1

  int tiles = (N + 63) / 64;
  int nchunks = (E + CHUNK - 1) / CHUNK;

  // CSR build first so dis is ready for gemm1's prescale epilogue
  hipMemsetAsync(bcur, 0, NBMAX * 4, stream);
  k_fillB<<<nchunks, 256, 0, stream>>>(ei, E, cap, bcur, tmp, nb);
  k_fillC<<<nb, 512, 0, stream>>>(tmp, bcur, cap, rowptr, dis, esrc, N, nb);

  // layer 1: t1 = dis .* (x @ W1) (fp16); z1 = relu(dv*(2*t1[v]+sum) + b1)
  k_gemm<128, false, true><<<tiles, 512, 0, stream>>>(x, W1, dis, t1, N, tiles);
  k_gather128<<<2048, 256, 0, stream>>>(t1, b1, rowptr, esrc, dis, z1, N);
  // layer 2: t2 = dis .* (z1 @ W2) (fp16); out = dv*(2*t2[v]+sum) + b2 (fp32)
  k_gemm<64, true, true><<<tiles, 256, 0, stream>>>(z1, W2, dis, t2, N, tiles);
  k_gather64<<<2048, 256, 0, stream>>>(t2, b2, rowptr, esrc, dis, out, N);
}